// Round 4
// baseline (2755.513 us; speedup 1.0000x reference)
//
#include <hip/hip_runtime.h>
#include <hip/hip_bf16.h>
#include <cstdint>
#include <cstddef>

typedef unsigned int uint;
typedef unsigned short ushort;
typedef _Float16 half2_t __attribute__((ext_vector_type(2)));

#define BATCH 256
#define SEQT  2048
#define FIN   32
#define HID   64
#define FH    64
#define NTOT  (BATCH*SEQT)

// ---------------- ws layout (f32 words) ----------------
enum : int {
  O_B0   = 0,                      // 256 (bih0+bhh0)
  O_B1   = O_B0 + 256,             // 256
  O_OW1  = O_B1 + 256,             // 64x9
  O_OB1  = O_OW1 + 64*9,
  O_OW2  = O_OB1 + 64,             // 64x64
  O_OB2  = O_OW2 + 64*64,
  O_OW3  = O_OB2 + 64,             // 8x64
  O_OB3  = O_OW3 + 8*64,
  O_OH0  = O_OB3 + 8,              // 8
  O_FW1  = O_OH0 + 8,              // 64x73
  O_FB1  = O_FW1 + 64*73,
  O_FW2  = O_FB1 + 64,             // 64x64
  O_FB2  = O_FW2 + 64*64,
  O_RW1  = O_FB2 + 64,             // 32x64
  O_RB1  = O_RW1 + 32*64,
  O_RW2  = O_RB1 + 32,             // 32
  O_RB2  = O_RW2 + 32,             // 1
  O_HW   = O_RB2 + 1,              // 8
  O_HB   = O_HW + 8,               // 1
  O_TRAJ = O_HB + 1,               // 366x8
  WS_F32_END = O_TRAJ + 366*8,
  // packed-f16 LSTM weights (1 uint = 2 f16), word offsets
  H_WIH0 = WS_F32_END,             // 256x16 uints
  H_WHH0 = H_WIH0 + 256*16,        // 256x32
  H_WIH1 = H_WHH0 + 256*32,        // 256x32
  H_WHH1 = H_WIH1 + 256*32,        // 256x32
  WS_END2 = H_WHH1 + 256*32
};

#define O_FLAG_BYTE  (500*1024)
#define ENV_BYTE_OFF (512*1024)

// ---------------- helpers ----------------
__device__ __forceinline__ float blo(uint u){ return __uint_as_float(u<<16); }
__device__ __forceinline__ float bhi(uint u){ return __uint_as_float(u & 0xffff0000u); }
__device__ __forceinline__ ushort f2b(float x){      // RNE f32 -> bf16
  uint u = __float_as_uint(x);
  uint r = u + 0x7fffu + ((u>>16)&1u);
  return (ushort)(r>>16);
}
__device__ __forceinline__ float sigm(float x){ return 1.0f/(1.0f+__expf(-x)); }
__device__ __forceinline__ float tanh_fast(float x){
  x = fminf(10.0f, fmaxf(-10.0f, x));
  float e = __expf(-2.0f*x);
  return (1.0f - e)/(1.0f + e);
}
__device__ __forceinline__ void wsync(){
  __builtin_amdgcn_wave_barrier();
  __threadfence_block();
  __builtin_amdgcn_wave_barrier();
}
__device__ __forceinline__ uint pkh2(float a, float b){
  half2_t h; h.x=(_Float16)a; h.y=(_Float16)b;
  return __builtin_bit_cast(uint, h);
}
__device__ __forceinline__ half2_t uph(uint u){ return __builtin_bit_cast(half2_t, u); }
__device__ __forceinline__ ushort hbits(float x){ return __builtin_bit_cast(ushort, (_Float16)x); }

#if __has_builtin(__builtin_amdgcn_fdot2)
__device__ __forceinline__ float FDOT2(half2_t a, half2_t b, float c){
  return __builtin_amdgcn_fdot2(a, b, c, false);
}
#else
__device__ __forceinline__ float FDOT2(half2_t a, half2_t b, float c){
  return c + (float)a.x*(float)b.x + (float)a.y*(float)b.y;
}
#endif

// ---------------- dtype detector ----------------
__global__ void detect_kernel(const uint* __restrict__ X, int* __restrict__ flagp) {
  if (threadIdx.x == 0) {
    int cnt = 0;
    for (int i=0;i<512;i++){
      uint e = (X[i]>>23)&0xFFu;
      cnt += (e>=97u && e<=157u) ? 1 : 0;
    }
    *flagp = (cnt >= 300) ? 1 : 0;   // 1 = float32 inputs, 0 = bf16 inputs
  }
}

// ---------------- prep ----------------
struct Ptrs { const void* p[28]; };

__global__ void prep_kernel(Ptrs ptrs, float* __restrict__ ws, const int* __restrict__ flagp) {
  const int flag = *flagp;
  const int tid = blockIdx.x*blockDim.x + threadIdx.x;
  const int nth = gridDim.x*blockDim.x;
  auto cv = [&](int dst, int srcidx, int n){
    if (flag) {
      const float* s = (const float*)ptrs.p[srcidx];
      for (int i=tid;i<n;i+=nth) ws[dst+i] = s[i];
    } else {
      const ushort* s = (const ushort*)ptrs.p[srcidx];
      for (int i=tid;i<n;i+=nth) ws[dst+i] = __uint_as_float(((uint)s[i])<<16);
    }
  };
  auto rd = [&](int srcidx, int i)->float{
    if (flag) return ((const float*)ptrs.p[srcidx])[i];
    return __uint_as_float(((uint)((const ushort*)ptrs.p[srcidx])[i])<<16);
  };
  auto cvh = [&](int dstw, int srcidx, int n2){
    uint* d = (uint*)ws;
    if (flag) {
      const float* s = (const float*)ptrs.p[srcidx];
      for (int i=tid;i<n2;i+=nth) d[dstw+i] = pkh2(s[2*i], s[2*i+1]);
    } else {
      const uint* s = (const uint*)ptrs.p[srcidx];
      for (int i=tid;i<n2;i+=nth){ uint u=s[i]; d[dstw+i] = pkh2(blo(u), bhi(u)); }
    }
  };
  cvh(H_WIH0,10,4096); cvh(H_WHH0,11,8192); cvh(H_WIH1,14,8192); cvh(H_WHH1,15,8192);
  for (int i=tid;i<256;i+=nth) ws[O_B0+i] = rd(12,i) + rd(13,i);
  for (int i=tid;i<256;i+=nth) ws[O_B1+i] = rd(16,i) + rd(17,i);
  cv(O_OW1,4,576); cv(O_OB1,5,64); cv(O_OW2,6,4096); cv(O_OB2,7,64);
  cv(O_OW3,8,512); cv(O_OB3,9,8);  cv(O_OH0,3,8);
  cv(O_FW1,20,4672); cv(O_FB1,21,64); cv(O_FW2,22,4096); cv(O_FB2,23,64);
  cv(O_RW1,24,2048); cv(O_RB1,25,32); cv(O_RW2,26,32); cv(O_RB2,27,1);
  cv(O_HW,18,8); cv(O_HB,19,1);
}

// ---------------- ODE (single wave 0, lockstep + fences) ----------------
__device__ void ode_wave(float* __restrict__ ws, float* sbuf) {
  const int lane = threadIdx.x;     // 0..63
  float* sZ1 = sbuf;
  float* sZ2 = sbuf + 64;
  float* sK  = sbuf + 128;

  float w1[9];
#pragma unroll
  for (int k=0;k<9;k++) w1[k]=ws[O_OW1+lane*9+k];
  const float b1 = ws[O_OB1+lane];
  float w2[64];
#pragma unroll
  for (int k=0;k<64;k++) w2[k]=ws[O_OW2+lane*64+k];
  const float b2 = ws[O_OB2+lane];
  const int m = lane>>3, s = lane&7;
  float w3[8];
#pragma unroll
  for (int k=0;k<8;k++) w3[k]=ws[O_OW3+m*64+s*8+k];
  const float b3m = ws[O_OB3+m];

  float h[8];
#pragma unroll
  for (int k=0;k<8;k++) h[k]=ws[O_OH0+k];

  {
    float sel = h[0];
#pragma unroll
    for (int i=1;i<8;i++) sel = (lane==i)? h[i] : sel;
    if (lane<8) ws[O_TRAJ+lane]=sel;
  }

  const float dt = 1.0f/365.0f;
  float k1[8],k2[8],k3[8],k4[8],k5[8],k6[8],ht[8];

  auto feval = [&](const float* hin, float te, float* kout) {
    float a = b1;
#pragma unroll
    for (int k=0;k<8;k++) a += w1[k]*hin[k];
    a += w1[8]*te;
    sZ1[lane] = tanh_fast(a);
    wsync();
    float acc = b2;
    {
      const float4* z4 = (const float4*)sZ1;
#pragma unroll
      for (int k=0;k<16;k++){ float4 v=z4[k];
        acc += w2[4*k]*v.x + w2[4*k+1]*v.y + w2[4*k+2]*v.z + w2[4*k+3]*v.w; }
    }
    sZ2[lane] = tanh_fast(acc);
    wsync();
    float part;
    {
      const float4* q = (const float4*)(sZ2 + s*8);
      float4 p0=q[0], p1=q[1];
      part = w3[0]*p0.x + w3[1]*p0.y + w3[2]*p0.z + w3[3]*p0.w
           + w3[4]*p1.x + w3[5]*p1.y + w3[6]*p1.z + w3[7]*p1.w;
    }
    part += __shfl_xor(part, 1);
    part += __shfl_xor(part, 2);
    part += __shfl_xor(part, 4);
    if (s==0) sK[m] = part + b3m;
    wsync();
    {
      const float4* kk = (const float4*)sK;
      float4 a0=kk[0], a1=kk[1];
      kout[0]=a0.x; kout[1]=a0.y; kout[2]=a0.z; kout[3]=a0.w;
      kout[4]=a1.x; kout[5]=a1.y; kout[6]=a1.z; kout[7]=a1.w;
    }
    wsync();
  };

  for (int d=0; d<365; d++) {
    float t0 = (float)d * dt;
    feval(h, t0, k1);
#pragma unroll
    for (int i=0;i<8;i++) ht[i] = h[i] + dt*(0.2f*k1[i]);
    feval(ht, t0 + 0.2f*dt, k2);
#pragma unroll
    for (int i=0;i<8;i++) ht[i] = h[i] + dt*((3.0f/40.0f)*k1[i] + (9.0f/40.0f)*k2[i]);
    feval(ht, t0 + 0.3f*dt, k3);
#pragma unroll
    for (int i=0;i<8;i++) ht[i] = h[i] + dt*((44.0f/45.0f)*k1[i] - (56.0f/15.0f)*k2[i] + (32.0f/9.0f)*k3[i]);
    feval(ht, t0 + 0.8f*dt, k4);
#pragma unroll
    for (int i=0;i<8;i++) ht[i] = h[i] + dt*((19372.0f/6561.0f)*k1[i] - (25360.0f/2187.0f)*k2[i]
                                   + (64448.0f/6561.0f)*k3[i] - (212.0f/729.0f)*k4[i]);
    feval(ht, t0 + (8.0f/9.0f)*dt, k5);
#pragma unroll
    for (int i=0;i<8;i++) ht[i] = h[i] + dt*((9017.0f/3168.0f)*k1[i] - (355.0f/33.0f)*k2[i]
                                   + (46732.0f/5247.0f)*k3[i] + (49.0f/176.0f)*k4[i]
                                   - (5103.0f/18656.0f)*k5[i]);
    feval(ht, t0 + dt, k6);
#pragma unroll
    for (int i=0;i<8;i++) h[i] += dt*((35.0f/384.0f)*k1[i] + (500.0f/1113.0f)*k3[i]
                                   + (125.0f/192.0f)*k4[i] - (2187.0f/6784.0f)*k5[i]
                                   + (11.0f/84.0f)*k6[i]);
    float sel = h[0];
#pragma unroll
    for (int i=1;i<8;i++) sel = (lane==i)? h[i] : sel;
    if (lane<8) ws[O_TRAJ + (d+1)*8 + lane] = sel;
  }
}

// ---------------- LSTM: SGPR-broadcast operands, LDS hist buffer ----------------
#define XCHUNK 128

__global__ __launch_bounds__(256, 1) void lstm_ode_kernel(const void* __restrict__ Xv,
                                                          float* __restrict__ ws,
                                                          ushort* __restrict__ env,
                                                          const int* __restrict__ flagp,
                                                          int b0, int runOde, int nb) {
  __shared__ __align__(16) uint  sxu[XCHUNK*16];   // x chunk, packed f16, 8 KB
  __shared__ __align__(16) uint  sHH[64];          // [0:32)=h1 pairs, [32:64)=h2 pairs (f16)
  __shared__ __align__(16) float sgA[256];         // layer0 gates (t)
  __shared__ __align__(16) float sgB[256];         // layer1 gates (t-1)
  __shared__ __align__(16) uint  shist[XCHUNK*32]; // h2 history, packed bf16 pairs, 16 KB

  if ((int)blockIdx.x == nb) {        // dedicated ODE block (slice 0 only)
    if (runOde && threadIdx.x < 64) ode_wave(ws, (float*)sxu);
    return;
  }

  const int flag = *flagp;
  const int b = b0 + blockIdx.x;
  const int j = threadIdx.x;
  const int l = j & 63;
  const uint* wsu = (const uint*)ws;

  // per-thread packed-f16 gate-row weights: 112 uints
  uint wx0[16], wh0[32], wh1[32], ww1[32];
  {
    const uint4* p = (const uint4*)(wsu + H_WIH0 + j*16);
#pragma unroll
    for (int q=0;q<4;q++){ uint4 v=p[q]; wx0[4*q]=v.x; wx0[4*q+1]=v.y; wx0[4*q+2]=v.z; wx0[4*q+3]=v.w; }
  }
  {
    const uint4* p = (const uint4*)(wsu + H_WHH0 + j*32);
#pragma unroll
    for (int q=0;q<8;q++){ uint4 v=p[q]; wh0[4*q]=v.x; wh0[4*q+1]=v.y; wh0[4*q+2]=v.z; wh0[4*q+3]=v.w; }
  }
  {
    const uint4* p = (const uint4*)(wsu + H_WIH1 + j*32);
#pragma unroll
    for (int q=0;q<8;q++){ uint4 v=p[q]; wh1[4*q]=v.x; wh1[4*q+1]=v.y; wh1[4*q+2]=v.z; wh1[4*q+3]=v.w; }
  }
  {
    const uint4* p = (const uint4*)(wsu + H_WHH1 + j*32);
#pragma unroll
    for (int q=0;q<8;q++){ uint4 v=p[q]; ww1[4*q]=v.x; ww1[4*q+1]=v.y; ww1[4*q+2]=v.z; ww1[4*q+3]=v.w; }
  }
  const float bias0 = ws[O_B0+j];
  const float bias1 = ws[O_B1+j];
  float cst = 0.0f;                   // c1[j] for j<64, c2[j-64] for 64<=j<128
  if (j < 64) sHH[j] = 0u;
  const uint*   xrow_b = (const uint*)Xv + (size_t)b*SEQT*(FIN/2);
  const float2* xrow_f = (const float2*)((const float*)Xv + (size_t)b*SEQT*FIN);
  uint* erow_u = (uint*)env + (size_t)blockIdx.x*SEQT*32;
  __syncthreads();

  // flush hist rows [baseT, baseT+128) -> env (coalesced uint stores)
  auto flush_hist = [&](int baseT){
#pragma unroll
    for (int i=0;i<16;i++){
      int idx = i*256 + j;              // 4096 uints
      erow_u[(size_t)(baseT + (idx>>5))*32 + (idx&31)] = shist[idx];
    }
  };

  for (int t=0; t<=SEQT; ++t) {
    if ((t & (XCHUNK-1)) == 0 && t < SEQT) {       // stage next x chunk as f16
      if (flag) {
        const float2* xc = xrow_f + t*(FIN/2);
#pragma unroll
        for (int it=0; it<(XCHUNK*16)/256; it++){
          int idx = it*256 + j;
          float2 v = xc[idx];
          sxu[idx] = pkh2(v.x, v.y);
        }
      } else {
        const uint* xc = xrow_b + t*(FIN/2);
#pragma unroll
        for (int it=0; it<(XCHUNK*16)/256; it++){
          int idx = it*256 + j;
          uint u = xc[idx];
          sxu[idx] = pkh2(blo(u), bhi(u));
        }
      }
      __syncthreads();
    }
    if ((t & (XCHUNK-1)) == 1 && t > 1) {
      // hist slots 0..127 hold h2(t-129..t-2); slot 0 is rewritten only in
      // Phase B of this step, which is after barrier #1 -> no extra sync.
      flush_hist(t-129);
    }
    const int tt = t & (XCHUNK-1);

    // ---- Phase A: gates via SGPR broadcasts
    uint vh = sHH[l];                               // 1 ds_read_b32 / wave
    uint vx = sxu[tt*16 + (l&15)];                  // 1 ds_read_b32 / wave
    float a0, a1;
    if (t < SEQT) {
      a0 = bias0; a1 = 0.0f;
#pragma unroll
      for (int k=0;k<16;k++){
        uint s = __builtin_amdgcn_readlane(vx, k);
        float& acc = (k&1) ? a1 : a0;
        acc = FDOT2(uph(wx0[k]), uph(s), acc);
      }
    } else { a0 = 0.0f; a1 = 0.0f; }
    float c0 = bias1, c1 = 0.0f;
#pragma unroll
    for (int k=0;k<32;k++){
      uint s = __builtin_amdgcn_readlane(vh, k);    // h1 pair k
      float& accA = (k&1) ? a1 : a0;
      float& accC = (k&1) ? c1 : c0;
      accA = FDOT2(uph(wh0[k]), uph(s), accA);
      accC = FDOT2(uph(wh1[k]), uph(s), accC);
    }
#pragma unroll
    for (int k=0;k<32;k++){
      uint s = __builtin_amdgcn_readlane(vh, 32+k); // h2 pair k
      float& accC = (k&1) ? c1 : c0;
      accC = FDOT2(uph(ww1[k]), uph(s), accC);
    }
    if (t < SEQT) sgA[j] = a0 + a1;
    if (t >= 1)   sgB[j] = c0 + c1;
    __syncthreads();                               // #1

    // ---- Phase B: cell updates (waves 0,1)
    if (t < SEQT && j < HID) {
      float gi=sgA[j], gf=sgA[HID+j], gg=sgA[2*HID+j], go=sgA[3*HID+j];
      cst = sigm(gf)*cst + sigm(gi)*tanh_fast(gg);
      float h1 = sigm(go)*tanh_fast(cst);
      ((ushort*)sHH)[j] = hbits(h1);
    } else if (t >= 1 && j >= HID && j < 2*HID) {
      int u = j - HID;
      float gi=sgB[u], gf=sgB[HID+u], gg=sgB[2*HID+u], go=sgB[3*HID+u];
      cst = sigm(gf)*cst + sigm(gi)*tanh_fast(gg);
      float h2 = sigm(go)*tanh_fast(cst);
      ((ushort*)sHH)[64 + u] = hbits(h2);
      ((ushort*)shist)[((t-1)&(XCHUNK-1))*64 + u] = f2b(h2);
    }
    __syncthreads();                               // #2
  }
  // final chunk: h2(1920..2047) in slots 0..127 (last write at t=2048, then #2)
  flush_hist(SEQT-XCHUNK);
}

// ---------------- fusion MLP + outputs ----------------
__global__ __launch_bounds__(256) void fuse_kernel(const ushort* __restrict__ envb,
                                                   const float* __restrict__ ws,
                                                   const int* __restrict__ day_ids,
                                                   const void* __restrict__ rawv,
                                                   void* __restrict__ outv,
                                                   const int* __restrict__ flagp,
                                                   int b0, int nb) {
  const int flag = *flagp;
  const int eloc = blockIdx.x*256 + threadIdx.x;
  const int bloc = eloc >> 11;
  const int b = b0 + bloc;
  const size_t ge = (size_t)b*SEQT + (eloc & 2047);

  int day = day_ids[b];
  day = day < 0 ? 0 : (day > 365 ? 365 : day);
  float hl[8];
#pragma unroll
  for (int i=0;i<8;i++) hl[i] = ws[O_TRAJ + day*8 + i];
  float rawD = ws[O_HB];
#pragma unroll
  for (int i=0;i<8;i++) rawD += hl[i]*ws[O_HW+i];
  const float Dv = sigm(rawD);

  float z[HID];
  {
    const uint4* ev = (const uint4*)(envb + (size_t)eloc*HID);
#pragma unroll
    for (int q=0;q<8;q++){
      uint4 u = ev[q];
      z[8*q+0]=blo(u.x); z[8*q+1]=bhi(u.x);
      z[8*q+2]=blo(u.y); z[8*q+3]=bhi(u.y);
      z[8*q+4]=blo(u.z); z[8*q+5]=bhi(u.z);
      z[8*q+6]=blo(u.w); z[8*q+7]=bhi(u.w);
    }
  }
  float G, Tc;
  if (flag) {
    float2 fr = ((const float2*)rawv)[ge*2];
    G = fr.x; Tc = fr.y;
  } else {
    uint gr = ((const uint*)rawv)[ge*2];
    G = blo(gr); Tc = bhi(gr);
  }
  const float Ip = G*9.0f*(1.0f + 0.0005f*(Tc-0.5f));

  float f1[FH];
#pragma unroll
  for (int jj=0;jj<FH;jj++){
    const float* wr = ws + O_FW1 + jj*73;
    float a = ws[O_FB1+jj];
#pragma unroll
    for (int k=0;k<HID;k++) a += wr[k]*z[k];
#pragma unroll
    for (int i=0;i<8;i++) a += wr[HID+i]*hl[i];
    a += wr[72]*Ip;
    f1[jj] = fmaxf(a,0.0f);
  }
  float f2[FH];
#pragma unroll
  for (int jj=0;jj<FH;jj++){
    const float* wr = ws + O_FW2 + jj*FH;
    float a = ws[O_FB2+jj];
#pragma unroll
    for (int k=0;k<FH;k++) a += wr[k]*f1[k];
    f2[jj] = fmaxf(a,0.0f);
  }
  float racc = ws[O_RB2];
#pragma unroll
  for (int mm=0;mm<32;mm++){
    const float* wr = ws + O_RW1 + mm*FH;
    float a = ws[O_RB1+mm];
#pragma unroll
    for (int k=0;k<FH;k++) a += wr[k]*f2[k];
    racc += ws[O_RW2+mm]*fmaxf(a,0.0f);
  }
  const float Ib = Dv*Ip;
  const float Ipred = Ib + racc;

  if (flag) {
    float* o = (float*)outv;
    o[ge] = Ipred; o[NTOT+ge] = Ip; o[(size_t)2*NTOT+ge] = Ib;
    o[(size_t)3*NTOT+ge] = Dv; o[(size_t)4*NTOT+ge] = racc;
    float4* hp = (float4*)(o + (size_t)5*NTOT + ge*8);
    hp[0] = make_float4(hl[0],hl[1],hl[2],hl[3]);
    hp[1] = make_float4(hl[4],hl[5],hl[6],hl[7]);
  } else {
    ushort* o = (ushort*)outv;
    o[ge] = f2b(Ipred); o[NTOT+ge] = f2b(Ip); o[(size_t)2*NTOT+ge] = f2b(Ib);
    o[(size_t)3*NTOT+ge] = f2b(Dv); o[(size_t)4*NTOT+ge] = f2b(racc);
    uint4 hsv;
    hsv.x = (uint)f2b(hl[0]) | ((uint)f2b(hl[1])<<16);
    hsv.y = (uint)f2b(hl[2]) | ((uint)f2b(hl[3])<<16);
    hsv.z = (uint)f2b(hl[4]) | ((uint)f2b(hl[5])<<16);
    hsv.w = (uint)f2b(hl[6]) | ((uint)f2b(hl[7])<<16);
    *((uint4*)(o + (size_t)5*NTOT + ge*8)) = hsv;
  }
}

// ---------------- launch ----------------
extern "C" void kernel_launch(void* const* d_in, const int* in_sizes, int n_in,
                              void* d_out, int out_size, void* d_ws, size_t ws_size,
                              hipStream_t stream) {
  (void)in_sizes; (void)out_size;
  float* wsf = (float*)d_ws;
  int* flagp = (int*)((char*)d_ws + O_FLAG_BYTE);
  ushort* env = (ushort*)((char*)d_ws + ENV_BYTE_OFF);
  Ptrs pa;
  for (int i=0;i<28;i++) pa.p[i] = (i<n_in) ? d_in[i] : d_in[0];

  int S = 1;
  while (S < 128) {
    size_t need = (size_t)ENV_BYTE_OFF + (size_t)(BATCH/S)*SEQT*HID*2;
    if (need <= ws_size) break;
    S <<= 1;
  }
  const int nb = BATCH / S;

  detect_kernel<<<1, 64, 0, stream>>>((const uint*)d_in[0], flagp);
  prep_kernel<<<128, 256, 0, stream>>>(pa, wsf, flagp);
  for (int s=0; s<S; s++) {
    lstm_ode_kernel<<<nb+1, 256, 0, stream>>>(d_in[0], wsf, env, flagp,
                                              s*nb, (s==0)?1:0, nb);
    fuse_kernel<<<nb*(SEQT/256), 256, 0, stream>>>(env, wsf, (const int*)d_in[1],
                                                   d_in[2], d_out, flagp, s*nb, nb);
  }
}

// Round 5
// 2424.557 us; speedup vs baseline: 1.1365x; 1.1365x over previous
//
#include <hip/hip_runtime.h>
#include <hip/hip_bf16.h>
#include <cstdint>
#include <cstddef>

typedef unsigned int uint;
typedef unsigned short ushort;
typedef _Float16 half2_t __attribute__((ext_vector_type(2)));

#define BATCH 256
#define SEQT  2048
#define FIN   32
#define HID   64
#define FH    64
#define NTOT  (BATCH*SEQT)

// ---------------- ws layout (f32 words) ----------------
enum : int {
  O_B0   = 0,                      // 256 (bih0+bhh0)
  O_B1   = O_B0 + 256,             // 256
  O_OW1  = O_B1 + 256,             // 64x9
  O_OB1  = O_OW1 + 64*9,
  O_OW2  = O_OB1 + 64,             // 64x64
  O_OB2  = O_OW2 + 64*64,
  O_OW3  = O_OB2 + 64,             // 8x64
  O_OB3  = O_OW3 + 8*64,
  O_OH0  = O_OB3 + 8,              // 8
  O_FW1  = O_OH0 + 8,              // 64x73
  O_FB1  = O_FW1 + 64*73,
  O_FW2  = O_FB1 + 64,             // 64x64
  O_FB2  = O_FW2 + 64*64,
  O_RW1  = O_FB2 + 64,             // 32x64
  O_RB1  = O_RW1 + 32*64,
  O_RW2  = O_RB1 + 32,             // 32
  O_RB2  = O_RW2 + 32,             // 1
  O_HW   = O_RB2 + 1,              // 8
  O_HB   = O_HW + 8,               // 1
  O_TRAJ = O_HB + 1,               // 366x8
  WS_F32_END = O_TRAJ + 366*8,
  // packed-f16 LSTM weights (1 uint = 2 f16), word offsets
  H_WIH0 = WS_F32_END,             // 256 rows x 16 uints
  H_WHH0 = H_WIH0 + 256*16,        // 256 x 32
  H_WIH1 = H_WHH0 + 256*32,        // 256 x 32
  H_WHH1 = H_WIH1 + 256*32,        // 256 x 32
  WS_END2 = H_WHH1 + 256*32
};

#define O_FLAG_BYTE  (500*1024)
#define ENV_BYTE_OFF (512*1024)

// ---------------- helpers ----------------
__device__ __forceinline__ float blo(uint u){ return __uint_as_float(u<<16); }
__device__ __forceinline__ float bhi(uint u){ return __uint_as_float(u & 0xffff0000u); }
__device__ __forceinline__ ushort f2b(float x){      // RNE f32 -> bf16
  uint u = __float_as_uint(x);
  uint r = u + 0x7fffu + ((u>>16)&1u);
  return (ushort)(r>>16);
}
__device__ __forceinline__ float sigm(float x){ return 1.0f/(1.0f+__expf(-x)); }
__device__ __forceinline__ float tanh_fast(float x){
  x = fminf(10.0f, fmaxf(-10.0f, x));
  float e = __expf(-2.0f*x);
  return (1.0f - e)/(1.0f + e);
}
__device__ __forceinline__ void wsync(){
  __builtin_amdgcn_wave_barrier();
  __threadfence_block();
  __builtin_amdgcn_wave_barrier();
}
__device__ __forceinline__ uint pkh2(float a, float b){
  half2_t h; h.x=(_Float16)a; h.y=(_Float16)b;
  return __builtin_bit_cast(uint, h);
}
__device__ __forceinline__ half2_t uph(uint u){ return __builtin_bit_cast(half2_t, u); }
__device__ __forceinline__ int hbits(float x){
  return (int)__builtin_bit_cast(ushort, (_Float16)x) & 0xFFFF;
}
// LDS-only release: lgkmcnt(0), vmcnt/expcnt untouched (do NOT drain global stores)
#define WAIT_LGKM0() __builtin_amdgcn_s_waitcnt(0xC07F)
#define MEMBAR()     asm volatile("" ::: "memory")

#if __has_builtin(__builtin_amdgcn_fdot2)
__device__ __forceinline__ float FDOT2(uint a, uint b, float c){
  return __builtin_amdgcn_fdot2(uph(a), uph(b), c, false);
}
#else
__device__ __forceinline__ float FDOT2(uint a, uint b, float c){
  half2_t x = uph(a), y = uph(b);
  return c + (float)x.x*(float)y.x + (float)x.y*(float)y.y;
}
#endif

// ---------------- dtype detector ----------------
__global__ void detect_kernel(const uint* __restrict__ X, int* __restrict__ flagp) {
  if (threadIdx.x == 0) {
    int cnt = 0;
    for (int i=0;i<512;i++){
      uint e = (X[i]>>23)&0xFFu;
      cnt += (e>=97u && e<=157u) ? 1 : 0;
    }
    *flagp = (cnt >= 300) ? 1 : 0;   // 1 = float32 inputs, 0 = bf16 inputs
  }
}

// ---------------- prep ----------------
struct Ptrs { const void* p[28]; };

__global__ void prep_kernel(Ptrs ptrs, float* __restrict__ ws, const int* __restrict__ flagp) {
  const int flag = *flagp;
  const int tid = blockIdx.x*blockDim.x + threadIdx.x;
  const int nth = gridDim.x*blockDim.x;
  auto cv = [&](int dst, int srcidx, int n){
    if (flag) {
      const float* s = (const float*)ptrs.p[srcidx];
      for (int i=tid;i<n;i+=nth) ws[dst+i] = s[i];
    } else {
      const ushort* s = (const ushort*)ptrs.p[srcidx];
      for (int i=tid;i<n;i+=nth) ws[dst+i] = __uint_as_float(((uint)s[i])<<16);
    }
  };
  auto rd = [&](int srcidx, int i)->float{
    if (flag) return ((const float*)ptrs.p[srcidx])[i];
    return __uint_as_float(((uint)((const ushort*)ptrs.p[srcidx])[i])<<16);
  };
  auto cvh = [&](int dstw, int srcidx, int n2){
    uint* d = (uint*)ws;
    if (flag) {
      const float* s = (const float*)ptrs.p[srcidx];
      for (int i=tid;i<n2;i+=nth) d[dstw+i] = pkh2(s[2*i], s[2*i+1]);
    } else {
      const uint* s = (const uint*)ptrs.p[srcidx];
      for (int i=tid;i<n2;i+=nth){ uint u=s[i]; d[dstw+i] = pkh2(blo(u), bhi(u)); }
    }
  };
  cvh(H_WIH0,10,4096); cvh(H_WHH0,11,8192); cvh(H_WIH1,14,8192); cvh(H_WHH1,15,8192);
  for (int i=tid;i<256;i+=nth) ws[O_B0+i] = rd(12,i) + rd(13,i);
  for (int i=tid;i<256;i+=nth) ws[O_B1+i] = rd(16,i) + rd(17,i);
  cv(O_OW1,4,576); cv(O_OB1,5,64); cv(O_OW2,6,4096); cv(O_OB2,7,64);
  cv(O_OW3,8,512); cv(O_OB3,9,8);  cv(O_OH0,3,8);
  cv(O_FW1,20,4672); cv(O_FB1,21,64); cv(O_FW2,22,4096); cv(O_FB2,23,64);
  cv(O_RW1,24,2048); cv(O_RB1,25,32); cv(O_RW2,26,32); cv(O_RB2,27,1);
  cv(O_HW,18,8); cv(O_HB,19,1);
}

// ---------------- ODE (single wave, lockstep + fences) ----------------
__device__ void ode_wave(float* __restrict__ ws, float* sbuf) {
  const int lane = threadIdx.x;     // 0..63
  float* sZ1 = sbuf;
  float* sZ2 = sbuf + 64;
  float* sK  = sbuf + 128;

  float w1[9];
#pragma unroll
  for (int k=0;k<9;k++) w1[k]=ws[O_OW1+lane*9+k];
  const float b1 = ws[O_OB1+lane];
  float w2[64];
#pragma unroll
  for (int k=0;k<64;k++) w2[k]=ws[O_OW2+lane*64+k];
  const float b2 = ws[O_OB2+lane];
  const int m = lane>>3, s = lane&7;
  float w3[8];
#pragma unroll
  for (int k=0;k<8;k++) w3[k]=ws[O_OW3+m*64+s*8+k];
  const float b3m = ws[O_OB3+m];

  float h[8];
#pragma unroll
  for (int k=0;k<8;k++) h[k]=ws[O_OH0+k];

  {
    float sel = h[0];
#pragma unroll
    for (int i=1;i<8;i++) sel = (lane==i)? h[i] : sel;
    if (lane<8) ws[O_TRAJ+lane]=sel;
  }

  const float dt = 1.0f/365.0f;
  float k1[8],k2[8],k3[8],k4[8],k5[8],k6[8],ht[8];

  auto feval = [&](const float* hin, float te, float* kout) {
    float a = b1;
#pragma unroll
    for (int k=0;k<8;k++) a += w1[k]*hin[k];
    a += w1[8]*te;
    sZ1[lane] = tanh_fast(a);
    wsync();
    float acc = b2;
    {
      const float4* z4 = (const float4*)sZ1;
#pragma unroll
      for (int k=0;k<16;k++){ float4 v=z4[k];
        acc += w2[4*k]*v.x + w2[4*k+1]*v.y + w2[4*k+2]*v.z + w2[4*k+3]*v.w; }
    }
    sZ2[lane] = tanh_fast(acc);
    wsync();
    float part;
    {
      const float4* q = (const float4*)(sZ2 + s*8);
      float4 p0=q[0], p1=q[1];
      part = w3[0]*p0.x + w3[1]*p0.y + w3[2]*p0.z + w3[3]*p0.w
           + w3[4]*p1.x + w3[5]*p1.y + w3[6]*p1.z + w3[7]*p1.w;
    }
    part += __shfl_xor(part, 1);
    part += __shfl_xor(part, 2);
    part += __shfl_xor(part, 4);
    if (s==0) sK[m] = part + b3m;
    wsync();
    {
      const float4* kk = (const float4*)sK;
      float4 a0=kk[0], a1=kk[1];
      kout[0]=a0.x; kout[1]=a0.y; kout[2]=a0.z; kout[3]=a0.w;
      kout[4]=a1.x; kout[5]=a1.y; kout[6]=a1.z; kout[7]=a1.w;
    }
    wsync();
  };

  for (int d=0; d<365; d++) {
    float t0 = (float)d * dt;
    feval(h, t0, k1);
#pragma unroll
    for (int i=0;i<8;i++) ht[i] = h[i] + dt*(0.2f*k1[i]);
    feval(ht, t0 + 0.2f*dt, k2);
#pragma unroll
    for (int i=0;i<8;i++) ht[i] = h[i] + dt*((3.0f/40.0f)*k1[i] + (9.0f/40.0f)*k2[i]);
    feval(ht, t0 + 0.3f*dt, k3);
#pragma unroll
    for (int i=0;i<8;i++) ht[i] = h[i] + dt*((44.0f/45.0f)*k1[i] - (56.0f/15.0f)*k2[i] + (32.0f/9.0f)*k3[i]);
    feval(ht, t0 + 0.8f*dt, k4);
#pragma unroll
    for (int i=0;i<8;i++) ht[i] = h[i] + dt*((19372.0f/6561.0f)*k1[i] - (25360.0f/2187.0f)*k2[i]
                                   + (64448.0f/6561.0f)*k3[i] - (212.0f/729.0f)*k4[i]);
    feval(ht, t0 + (8.0f/9.0f)*dt, k5);
#pragma unroll
    for (int i=0;i<8;i++) ht[i] = h[i] + dt*((9017.0f/3168.0f)*k1[i] - (355.0f/33.0f)*k2[i]
                                   + (46732.0f/5247.0f)*k3[i] + (49.0f/176.0f)*k4[i]
                                   - (5103.0f/18656.0f)*k5[i]);
    feval(ht, t0 + dt, k6);
#pragma unroll
    for (int i=0;i<8;i++) h[i] += dt*((35.0f/384.0f)*k1[i] + (500.0f/1113.0f)*k3[i]
                                   + (125.0f/192.0f)*k4[i] - (2187.0f/6784.0f)*k5[i]
                                   + (11.0f/84.0f)*k6[i]);
    float sel = h[0];
#pragma unroll
    for (int i=1;i<8;i++) sel = (lane==i)? h[i] : sel;
    if (lane<8) ws[O_TRAJ + (d+1)*8 + lane] = sel;
  }
}

// ---------------- LSTM: 3-wave barrier-free pipeline per sample ----------------
// wave0: full layer-0 recurrence (lane j = unit j, all 4 gates). publishes h1 ring.
// wave1: Wih1 . h1(t)  -> partial ring.
// wave2: Whh1 . h2(t-1) + partial -> cell -> env (f16 pairs), h2 stays in-wave.
#define RH 64     // h1 ring slots
#define RP 16     // partial ring slots

__global__ __launch_bounds__(192) void lstm_pipe_kernel(const void* __restrict__ Xv,
                                                        float* __restrict__ ws,
                                                        ushort* __restrict__ env,
                                                        const int* __restrict__ flagp,
                                                        int b0, int runOde, int nb) {
  __shared__ __align__(16) uint  sx[128*16];       // x pairs chunk (f16), 8 KB
  __shared__ __align__(16) uint  ringH[RH*32];     // h1 f16-pair ring, 8 KB
  __shared__ __align__(16) float ringP[RP*256];    // L1 partial ring, 16 KB
  __shared__ int cnts[4];                          // 0:c_h1 1:c_p 2:c_done

  if ((int)blockIdx.x == nb) {        // dedicated ODE block
    if (runOde && threadIdx.x < 64) ode_wave(ws, (float*)sx);
    return;
  }

  const int flag = *flagp;
  const int b = b0 + blockIdx.x;
  const int wave = threadIdx.x >> 6;
  const int lane = threadIdx.x & 63;
  const uint* wsu = (const uint*)ws;
  if (threadIdx.x < 4) cnts[threadIdx.x] = -1;
  __syncthreads();                    // the only block barrier (init)
  volatile int* vc = cnts;

  if (wave == 0) {
    // ---- layer-0 owner ----
    uint wx[4][16], wh[4][32];
    float bias[4];
#pragma unroll
    for (int g=0; g<4; g++){
      const uint4* p = (const uint4*)(wsu + H_WIH0 + (g*64+lane)*16);
#pragma unroll
      for (int q=0;q<4;q++){ uint4 v=p[q]; wx[g][4*q]=v.x; wx[g][4*q+1]=v.y; wx[g][4*q+2]=v.z; wx[g][4*q+3]=v.w; }
      const uint4* r = (const uint4*)(wsu + H_WHH0 + (g*64+lane)*32);
#pragma unroll
      for (int q=0;q<8;q++){ uint4 v=r[q]; wh[g][4*q]=v.x; wh[g][4*q+1]=v.y; wh[g][4*q+2]=v.z; wh[g][4*q+3]=v.w; }
      bias[g] = ws[O_B0 + g*64 + lane];
    }
    const uint4*   xb4 = (const uint4*)((const uint*)Xv + (size_t)b*SEQT*16);
    const float4*  xf4 = (const float4*)((const float*)Xv + (size_t)b*SEQT*FIN);
    float c1 = 0.0f;
    uint vh1pk = 0u;                      // lane p (p<32) holds h1 pair p (f16)

    for (int t=0; t<SEQT; ++t) {
      if ((t & 127) == 0) {               // stage x chunk (wave-private, no barrier)
        if (flag) {
#pragma unroll
          for (int i=0;i<16;i++){
            float4 v = xf4[(size_t)(t>>2)*8 /*t*32/4*/ + i*64 + lane];
            uint2 w; w.x = pkh2(v.x,v.y); w.y = pkh2(v.z,v.w);
            ((uint2*)sx)[i*64 + lane] = w;
          }
        } else {
#pragma unroll
          for (int i=0;i<8;i++){
            uint4 u = xb4[(size_t)t*4 + i*64 + lane];
            uint4 w;
            w.x = pkh2(blo(u.x), bhi(u.x)); w.y = pkh2(blo(u.y), bhi(u.y));
            w.z = pkh2(blo(u.z), bhi(u.z)); w.w = pkh2(blo(u.w), bhi(u.w));
            ((uint4*)sx)[i*64 + lane] = w;
          }
        }
      }
      // pace: don't overwrite ringH slot before w1 consumed it
      while (vc[1] < t - RH) { __builtin_amdgcn_s_sleep(1); }

      uint vx = sx[(t&127)*16 + (lane&15)];   // pair (lane&15) for this step
      float a[4] = {bias[0], bias[1], bias[2], bias[3]};
      float z[4] = {0.f,0.f,0.f,0.f};
#pragma unroll
      for (int k=0;k<16;k++){
        uint s = (uint)__builtin_amdgcn_readlane((int)vx, k);
        if (k&1){ z[0]=FDOT2(wx[0][k],s,z[0]); z[1]=FDOT2(wx[1][k],s,z[1]);
                  z[2]=FDOT2(wx[2][k],s,z[2]); z[3]=FDOT2(wx[3][k],s,z[3]); }
        else    { a[0]=FDOT2(wx[0][k],s,a[0]); a[1]=FDOT2(wx[1][k],s,a[1]);
                  a[2]=FDOT2(wx[2][k],s,a[2]); a[3]=FDOT2(wx[3][k],s,a[3]); }
      }
#pragma unroll
      for (int k=0;k<32;k++){
        uint s = (uint)__builtin_amdgcn_readlane((int)vh1pk, k);
        if (k&1){ z[0]=FDOT2(wh[0][k],s,z[0]); z[1]=FDOT2(wh[1][k],s,z[1]);
                  z[2]=FDOT2(wh[2][k],s,z[2]); z[3]=FDOT2(wh[3][k],s,z[3]); }
        else    { a[0]=FDOT2(wh[0][k],s,a[0]); a[1]=FDOT2(wh[1][k],s,a[1]);
                  a[2]=FDOT2(wh[2][k],s,a[2]); a[3]=FDOT2(wh[3][k],s,a[3]); }
      }
      float gi=a[0]+z[0], gf=a[1]+z[1], gg=a[2]+z[2], go=a[3]+z[3];
      c1 = sigm(gf)*c1 + sigm(gi)*tanh_fast(gg);
      float h1 = sigm(go)*tanh_fast(c1);
      int hb = hbits(h1);
      uint lo = (uint)__shfl(hb, 2*lane);
      uint hi = (uint)__shfl(hb, 2*lane+1);
      vh1pk = lo | (hi<<16);
      if (lane < 32) ringH[(t&(RH-1))*32 + lane] = vh1pk;
      WAIT_LGKM0(); MEMBAR();
      if (lane == 0) vc[0] = t;
    }
  } else if (wave == 1) {
    // ---- L1 h1-part ----
    uint wi[4][32];
    float bias1[4];
#pragma unroll
    for (int g=0; g<4; g++){
      const uint4* p = (const uint4*)(wsu + H_WIH1 + (g*64+lane)*32);
#pragma unroll
      for (int q=0;q<8;q++){ uint4 v=p[q]; wi[g][4*q]=v.x; wi[g][4*q+1]=v.y; wi[g][4*q+2]=v.z; wi[g][4*q+3]=v.w; }
      bias1[g] = ws[O_B1 + g*64 + lane];
    }
    for (int t=0; t<SEQT; ++t) {
      while (vc[0] < t)      { __builtin_amdgcn_s_sleep(1); }
      while (vc[2] < t - RP) { __builtin_amdgcn_s_sleep(1); }
      MEMBAR();
      uint vh = ringH[(t&(RH-1))*32 + (lane&31)];
      float p0=bias1[0], p1=bias1[1], p2=bias1[2], p3=bias1[3];
      float q0=0.f, q1=0.f, q2=0.f, q3=0.f;
#pragma unroll
      for (int k=0;k<32;k++){
        uint s = (uint)__builtin_amdgcn_readlane((int)vh, k);
        if (k&1){ q0=FDOT2(wi[0][k],s,q0); q1=FDOT2(wi[1][k],s,q1);
                  q2=FDOT2(wi[2][k],s,q2); q3=FDOT2(wi[3][k],s,q3); }
        else    { p0=FDOT2(wi[0][k],s,p0); p1=FDOT2(wi[1][k],s,p1);
                  p2=FDOT2(wi[2][k],s,p2); p3=FDOT2(wi[3][k],s,p3); }
      }
      ((float4*)(ringP + (t&(RP-1))*256))[lane] = make_float4(p0+q0, p1+q1, p2+q2, p3+q3);
      WAIT_LGKM0(); MEMBAR();
      if (lane == 0) vc[1] = t;
    }
  } else {
    // ---- L1 h2-part + cell + env ----
    uint wh2[4][32];
#pragma unroll
    for (int g=0; g<4; g++){
      const uint4* p = (const uint4*)(wsu + H_WHH1 + (g*64+lane)*32);
#pragma unroll
      for (int q=0;q<8;q++){ uint4 v=p[q]; wh2[g][4*q]=v.x; wh2[g][4*q+1]=v.y; wh2[g][4*q+2]=v.z; wh2[g][4*q+3]=v.w; }
    }
    uint* erow = (uint*)env + (size_t)blockIdx.x*SEQT*32;
    float c2 = 0.0f;
    uint vh2pk = 0u;
    for (int t=0; t<SEQT; ++t) {
      while (vc[1] < t) { __builtin_amdgcn_s_sleep(1); }
      MEMBAR();
      float4 pp = ((const float4*)(ringP + (t&(RP-1))*256))[lane];
      float a0=0.f,a1=0.f,a2=0.f,a3=0.f, z0=0.f,z1=0.f,z2=0.f,z3=0.f;
#pragma unroll
      for (int k=0;k<32;k++){
        uint s = (uint)__builtin_amdgcn_readlane((int)vh2pk, k);
        if (k&1){ z0=FDOT2(wh2[0][k],s,z0); z1=FDOT2(wh2[1][k],s,z1);
                  z2=FDOT2(wh2[2][k],s,z2); z3=FDOT2(wh2[3][k],s,z3); }
        else    { a0=FDOT2(wh2[0][k],s,a0); a1=FDOT2(wh2[1][k],s,a1);
                  a2=FDOT2(wh2[2][k],s,a2); a3=FDOT2(wh2[3][k],s,a3); }
      }
      float gi=pp.x+a0+z0, gf=pp.y+a1+z1, gg=pp.z+a2+z2, go=pp.w+a3+z3;
      c2 = sigm(gf)*c2 + sigm(gi)*tanh_fast(gg);
      float h2 = sigm(go)*tanh_fast(c2);
      int hb = hbits(h2);
      uint lo = (uint)__shfl(hb, 2*lane);
      uint hi = (uint)__shfl(hb, 2*lane+1);
      vh2pk = lo | (hi<<16);
      if (lane < 32) erow[(size_t)t*32 + lane] = vh2pk;   // env as f16 pairs
      WAIT_LGKM0(); MEMBAR();
      if (lane == 0) vc[2] = t;
    }
  }
}

// ---------------- fusion MLP + outputs (env is f16 pairs now) ----------------
__global__ __launch_bounds__(256) void fuse_kernel(const ushort* __restrict__ envb,
                                                   const float* __restrict__ ws,
                                                   const int* __restrict__ day_ids,
                                                   const void* __restrict__ rawv,
                                                   void* __restrict__ outv,
                                                   const int* __restrict__ flagp,
                                                   int b0, int nb) {
  const int flag = *flagp;
  const int eloc = blockIdx.x*256 + threadIdx.x;
  const int bloc = eloc >> 11;
  const int b = b0 + bloc;
  const size_t ge = (size_t)b*SEQT + (eloc & 2047);

  int day = day_ids[b];
  day = day < 0 ? 0 : (day > 365 ? 365 : day);
  float hl[8];
#pragma unroll
  for (int i=0;i<8;i++) hl[i] = ws[O_TRAJ + day*8 + i];
  float rawD = ws[O_HB];
#pragma unroll
  for (int i=0;i<8;i++) rawD += hl[i]*ws[O_HW+i];
  const float Dv = sigm(rawD);

  float z[HID];
  {
    const uint4* ev = (const uint4*)(envb + (size_t)eloc*HID);
#pragma unroll
    for (int q=0;q<8;q++){
      uint4 u = ev[q];
      half2_t h0=uph(u.x), h1=uph(u.y), h2=uph(u.z), h3=uph(u.w);
      z[8*q+0]=(float)h0.x; z[8*q+1]=(float)h0.y;
      z[8*q+2]=(float)h1.x; z[8*q+3]=(float)h1.y;
      z[8*q+4]=(float)h2.x; z[8*q+5]=(float)h2.y;
      z[8*q+6]=(float)h3.x; z[8*q+7]=(float)h3.y;
    }
  }
  float G, Tc;
  if (flag) {
    float2 fr = ((const float2*)rawv)[ge*2];
    G = fr.x; Tc = fr.y;
  } else {
    uint gr = ((const uint*)rawv)[ge*2];
    G = blo(gr); Tc = bhi(gr);
  }
  const float Ip = G*9.0f*(1.0f + 0.0005f*(Tc-0.5f));

  float f1[FH];
#pragma unroll
  for (int jj=0;jj<FH;jj++){
    const float* wr = ws + O_FW1 + jj*73;
    float a = ws[O_FB1+jj];
#pragma unroll
    for (int k=0;k<HID;k++) a += wr[k]*z[k];
#pragma unroll
    for (int i=0;i<8;i++) a += wr[HID+i]*hl[i];
    a += wr[72]*Ip;
    f1[jj] = fmaxf(a,0.0f);
  }
  float f2[FH];
#pragma unroll
  for (int jj=0;jj<FH;jj++){
    const float* wr = ws + O_FW2 + jj*FH;
    float a = ws[O_FB2+jj];
#pragma unroll
    for (int k=0;k<FH;k++) a += wr[k]*f1[k];
    f2[jj] = fmaxf(a,0.0f);
  }
  float racc = ws[O_RB2];
#pragma unroll
  for (int mm=0;mm<32;mm++){
    const float* wr = ws + O_RW1 + mm*FH;
    float a = ws[O_RB1+mm];
#pragma unroll
    for (int k=0;k<FH;k++) a += wr[k]*f2[k];
    racc += ws[O_RW2+mm]*fmaxf(a,0.0f);
  }
  const float Ib = Dv*Ip;
  const float Ipred = Ib + racc;

  if (flag) {
    float* o = (float*)outv;
    o[ge] = Ipred; o[NTOT+ge] = Ip; o[(size_t)2*NTOT+ge] = Ib;
    o[(size_t)3*NTOT+ge] = Dv; o[(size_t)4*NTOT+ge] = racc;
    float4* hp = (float4*)(o + (size_t)5*NTOT + ge*8);
    hp[0] = make_float4(hl[0],hl[1],hl[2],hl[3]);
    hp[1] = make_float4(hl[4],hl[5],hl[6],hl[7]);
  } else {
    ushort* o = (ushort*)outv;
    o[ge] = f2b(Ipred); o[NTOT+ge] = f2b(Ip); o[(size_t)2*NTOT+ge] = f2b(Ib);
    o[(size_t)3*NTOT+ge] = f2b(Dv); o[(size_t)4*NTOT+ge] = f2b(racc);
    uint4 hsv;
    hsv.x = (uint)f2b(hl[0]) | ((uint)f2b(hl[1])<<16);
    hsv.y = (uint)f2b(hl[2]) | ((uint)f2b(hl[3])<<16);
    hsv.z = (uint)f2b(hl[4]) | ((uint)f2b(hl[5])<<16);
    hsv.w = (uint)f2b(hl[6]) | ((uint)f2b(hl[7])<<16);
    *((uint4*)(o + (size_t)5*NTOT + ge*8)) = hsv;
  }
}

// ---------------- launch ----------------
extern "C" void kernel_launch(void* const* d_in, const int* in_sizes, int n_in,
                              void* d_out, int out_size, void* d_ws, size_t ws_size,
                              hipStream_t stream) {
  (void)in_sizes; (void)out_size;
  float* wsf = (float*)d_ws;
  int* flagp = (int*)((char*)d_ws + O_FLAG_BYTE);
  ushort* env = (ushort*)((char*)d_ws + ENV_BYTE_OFF);
  Ptrs pa;
  for (int i=0;i<28;i++) pa.p[i] = (i<n_in) ? d_in[i] : d_in[0];

  int S = 1;
  while (S < 128) {
    size_t need = (size_t)ENV_BYTE_OFF + (size_t)(BATCH/S)*SEQT*HID*2;
    if (need <= ws_size) break;
    S <<= 1;
  }
  const int nb = BATCH / S;

  detect_kernel<<<1, 64, 0, stream>>>((const uint*)d_in[0], flagp);
  prep_kernel<<<128, 256, 0, stream>>>(pa, wsf, flagp);
  for (int s=0; s<S; s++) {
    lstm_pipe_kernel<<<nb+1, 192, 0, stream>>>(d_in[0], wsf, env, flagp,
                                               s*nb, (s==0)?1:0, nb);
    fuse_kernel<<<nb*(SEQT/256), 256, 0, stream>>>(env, wsf, (const int*)d_in[1],
                                                   d_in[2], d_out, flagp, s*nb, nb);
  }
}